// Round 3
// baseline (18278.770 us; speedup 1.0000x reference)
//
#include <hip/hip_runtime.h>
#include <stdint.h>

#define B_   128
#define T_   64
#define V_   1024
#define TS_  64
#define H_   512
#define K_   (V_ + TS_)   // 1088

// ---------------------------------------------------------------------------
// Fully fused time-aware GRU scan, round 3.
//
// 256 workgroups x 1 wave (co-resident, one per CU). WG g owns h[2g], h[2g+1].
// Register-resident weights: 6 rows W_hh (48 VGPRs) + 6 rows W_ih (102 VGPRs).
//
// h exchange: double-buffered [2][512] array of 64-bit words,
// (version<<32)|float_bits.
//   - WRITE: agent-scope relaxed atomic store (bypasses L1/L2 -> LLC).
//   - READ (the round-2 lesson): agent-scope atomic loads in a spin loop
//     melt the LLC -- 256 WGs x 512 uncacheable loads/iter onto the same 32
//     lines ~= 600G req/s vs ~64G/s same-line capacity -> 2.8us/step measured.
//     Round 3 polls with PLAIN (workgroup-scope atomic) loads, which are
//     L1/L2-cacheable and MSHR-merge per XCD (~256 LLC req/iter total),
//     preceded each iteration by an agent-scope acquire fence (buffer_inv)
//     to discard stale lines. Per-word version tags make store->load
//     ordering irrelevant; every 64th iteration falls back to agent-scope
//     atomic loads as a forward-progress guarantee.
//
// Masked steps (t >= lens[b]) are identity and skipped; chain length is
// sum(lens) ~= 4032, not B*T.
// Workspace: 8 KiB h_buf only. Poison 0xAAAAAAAA never equals a version tag.
// ---------------------------------------------------------------------------

__device__ __forceinline__ float sigmoidf_(float x) {
    return 1.0f / (1.0f + __expf(-x));
}
__device__ __forceinline__ float tanhf_(float x) {
    x = fminf(fmaxf(x, -15.0f), 15.0f);
    const float e = __expf(2.0f * x);
    return (e - 1.0f) / (e + 1.0f);
}

__global__ __launch_bounds__(64, 1) void gru_fused(
    const float* __restrict__ visit_emb, const float* __restrict__ intervals,
    const float* __restrict__ W_time, const float* __restrict__ b_time,
    const float* __restrict__ W_ih, const float* __restrict__ W_hh,
    const float* __restrict__ b_ih, const float* __restrict__ b_hh,
    const int* __restrict__ lens, uint64_t* h_buf /* [2][H_] */,
    float* __restrict__ out)
{
    const int wg   = blockIdx.x;      // 0..255
    const int lane = threadIdx.x;     // 0..63
    const int j0   = wg * 2;
    const int j1   = j0 + 1;

    // ---- register-resident W_hh rows (k = lane + 64u) -------------------
    float wr0[8], wr1[8], wz0[8], wz1[8], wn0[8], wn1[8];
    #pragma unroll
    for (int u = 0; u < 8; ++u) {
        const int k = lane + 64 * u;
        wr0[u] = W_hh[(size_t)j0 * H_ + k];
        wr1[u] = W_hh[(size_t)j1 * H_ + k];
        wz0[u] = W_hh[(size_t)(H_ + j0) * H_ + k];
        wz1[u] = W_hh[(size_t)(H_ + j1) * H_ + k];
        wn0[u] = W_hh[(size_t)(2 * H_ + j0) * H_ + k];
        wn1[u] = W_hh[(size_t)(2 * H_ + j1) * H_ + k];
    }
    // ---- register-resident W_ih rows: u<16 visit part, u==16 time part --
    float ir0[17], ir1[17], iz0[17], iz1[17], in0[17], in1[17];
    #pragma unroll
    for (int u = 0; u < 16; ++u) {
        const int k = lane + 64 * u;
        ir0[u] = W_ih[(size_t)j0 * K_ + k];
        ir1[u] = W_ih[(size_t)j1 * K_ + k];
        iz0[u] = W_ih[(size_t)(H_ + j0) * K_ + k];
        iz1[u] = W_ih[(size_t)(H_ + j1) * K_ + k];
        in0[u] = W_ih[(size_t)(2 * H_ + j0) * K_ + k];
        in1[u] = W_ih[(size_t)(2 * H_ + j1) * K_ + k];
    }
    ir0[16] = W_ih[(size_t)j0 * K_ + V_ + lane];
    ir1[16] = W_ih[(size_t)j1 * K_ + V_ + lane];
    iz0[16] = W_ih[(size_t)(H_ + j0) * K_ + V_ + lane];
    iz1[16] = W_ih[(size_t)(H_ + j1) * K_ + V_ + lane];
    in0[16] = W_ih[(size_t)(2 * H_ + j0) * K_ + V_ + lane];
    in1[16] = W_ih[(size_t)(2 * H_ + j1) * K_ + V_ + lane];

    const float wt = W_time[lane];    // time-emb weight/bias for ts = lane
    const float bt = b_time[lane];

    const float bir0 = b_ih[j0],          bir1 = b_ih[j1];
    const float biz0 = b_ih[H_ + j0],     biz1 = b_ih[H_ + j1];
    const float bin0 = b_ih[2 * H_ + j0], bin1 = b_ih[2 * H_ + j1];
    const float bhr0 = b_hh[j0],          bhr1 = b_hh[j1];
    const float bhz0 = b_hh[H_ + j0],     bhz1 = b_hh[H_ + j1];
    const float bhn0 = b_hh[2 * H_ + j0], bhn1 = b_hh[2 * H_ + j1];

    float hj0 = 0.0f, hj1 = 0.0f;
    uint32_t ver = 1;  // version 1 == initial zero state

    if (lane == 0)
        __hip_atomic_store(&h_buf[(ver & 1) * H_ + j0], (uint64_t)ver << 32,
                           __ATOMIC_RELAXED, __HIP_MEMORY_SCOPE_AGENT);
    if (lane == 1)
        __hip_atomic_store(&h_buf[(ver & 1) * H_ + j1], (uint64_t)ver << 32,
                           __ATOMIC_RELAXED, __HIP_MEMORY_SCOPE_AGENT);

    for (int b = 0; b < B_; ++b) {
        const int L = lens[b];
        for (int t = 0; t < L; ++t) {
            // ---- x-side: independent of h, overlaps the h round-trip ----
            const float iv = intervals[b * T_ + t];
            const float* vrow = visit_emb + (size_t)(b * T_ + t) * V_;
            float xv[16];
            #pragma unroll
            for (int u = 0; u < 16; ++u) xv[u] = vrow[lane + 64 * u];
            const float xt = fmaf(iv, wt, bt);

            float ar0 = ir0[16] * xt, ar1 = ir1[16] * xt;
            float az0 = iz0[16] * xt, az1 = iz1[16] * xt;
            float xn0 = in0[16] * xt, xn1 = in1[16] * xt;
            #pragma unroll
            for (int u = 0; u < 16; ++u) {
                ar0 = fmaf(ir0[u], xv[u], ar0);
                ar1 = fmaf(ir1[u], xv[u], ar1);
                az0 = fmaf(iz0[u], xv[u], az0);
                az1 = fmaf(iz1[u], xv[u], az1);
                xn0 = fmaf(in0[u], xv[u], xn0);
                xn1 = fmaf(in1[u], xv[u], xn1);
            }

            // ---- poll current h version via CACHEABLE loads -------------
            // acquire fence (buffer_inv) each iteration discards stale
            // L1/L2 lines; loads then refill from LLC, MSHR-merged per XCD.
            const uint64_t* src = h_buf + (ver & 1) * H_;
            uint64_t w[8];
            int  spins = 0;
            bool ok;
            do {
                __builtin_amdgcn_fence(__ATOMIC_ACQUIRE, "agent");
                ok = true;
                if (__builtin_expect(++spins < 64, 1)) {
                    #pragma unroll
                    for (int u = 0; u < 8; ++u) {
                        w[u] = __hip_atomic_load(&src[lane + 64 * u],
                                                 __ATOMIC_RELAXED,
                                                 __HIP_MEMORY_SCOPE_WORKGROUP);
                        ok = ok && ((uint32_t)(w[u] >> 32) == ver);
                    }
                } else {
                    // forward-progress hedge: uncacheable path, rarely taken
                    spins = 0;
                    #pragma unroll
                    for (int u = 0; u < 8; ++u) {
                        w[u] = __hip_atomic_load(&src[lane + 64 * u],
                                                 __ATOMIC_RELAXED,
                                                 __HIP_MEMORY_SCOPE_AGENT);
                        ok = ok && ((uint32_t)(w[u] >> 32) == ver);
                    }
                }
            } while (!__all(ok));

            float h[8];
            #pragma unroll
            for (int u = 0; u < 8; ++u) h[u] = __uint_as_float((uint32_t)w[u]);

            // ---- h-side dots; r/z merged with x-side, n kept split ------
            float hn0 = 0.0f, hn1 = 0.0f;
            #pragma unroll
            for (int u = 0; u < 8; ++u) {
                ar0 = fmaf(wr0[u], h[u], ar0);
                ar1 = fmaf(wr1[u], h[u], ar1);
                az0 = fmaf(wz0[u], h[u], az0);
                az1 = fmaf(wz1[u], h[u], az1);
                hn0 = fmaf(wn0[u], h[u], hn0);
                hn1 = fmaf(wn1[u], h[u], hn1);
            }
            // ---- single 8-value wave butterfly --------------------------
            #pragma unroll
            for (int m = 1; m < 64; m <<= 1) {
                ar0 += __shfl_xor(ar0, m, 64);
                ar1 += __shfl_xor(ar1, m, 64);
                az0 += __shfl_xor(az0, m, 64);
                az1 += __shfl_xor(az1, m, 64);
                xn0 += __shfl_xor(xn0, m, 64);
                xn1 += __shfl_xor(xn1, m, 64);
                hn0 += __shfl_xor(hn0, m, 64);
                hn1 += __shfl_xor(hn1, m, 64);
            }

            const float r0 = sigmoidf_(ar0 + bir0 + bhr0);
            const float r1 = sigmoidf_(ar1 + bir1 + bhr1);
            const float z0 = sigmoidf_(az0 + biz0 + bhz0);
            const float z1 = sigmoidf_(az1 + biz1 + bhz1);
            const float n0 = tanhf_(xn0 + bin0 + r0 * (hn0 + bhn0));
            const float n1 = tanhf_(xn1 + bin1 + r1 * (hn1 + bhn1));
            hj0 = (1.0f - z0) * n0 + z0 * hj0;
            hj1 = (1.0f - z1) * n1 + z1 * hj1;

            // ---- publish h' with embedded version tag (straight to LLC) -
            ++ver;
            uint64_t* dst = h_buf + (ver & 1) * H_;
            if (lane == 0)
                __hip_atomic_store(&dst[j0],
                    ((uint64_t)ver << 32) | (uint64_t)__float_as_uint(hj0),
                    __ATOMIC_RELAXED, __HIP_MEMORY_SCOPE_AGENT);
            if (lane == 1)
                __hip_atomic_store(&dst[j1],
                    ((uint64_t)ver << 32) | (uint64_t)__float_as_uint(hj1),
                    __ATOMIC_RELAXED, __HIP_MEMORY_SCOPE_AGENT);
        }
        // out[b] = h after sample b's (possibly empty) segment
        if (lane == 0) out[b * H_ + j0] = hj0;
        if (lane == 1) out[b * H_ + j1] = hj1;
    }
}

// ---------------------------------------------------------------------------
extern "C" void kernel_launch(void* const* d_in, const int* in_sizes, int n_in,
                              void* d_out, int out_size, void* d_ws, size_t ws_size,
                              hipStream_t stream)
{
    const float* visit_emb = (const float*)d_in[0];
    const float* intervals = (const float*)d_in[1];
    const float* W_time    = (const float*)d_in[2];
    const float* b_time    = (const float*)d_in[3];
    const float* W_ih      = (const float*)d_in[4];
    const float* W_hh      = (const float*)d_in[5];
    const float* b_ih      = (const float*)d_in[6];
    const float* b_hh      = (const float*)d_in[7];
    const int*   lens      = (const int*)d_in[8];
    float*       out       = (float*)d_out;

    // workspace: only the h exchange buffer (2 x 512 x u64 = 8 KiB)
    uint64_t* h_buf = (uint64_t*)d_ws;

    gru_fused<<<256, 64, 0, stream>>>(visit_emb, intervals, W_time, b_time,
                                      W_ih, W_hh, b_ih, b_hh, lens, h_buf, out);
}

// Round 6
// 8980.382 us; speedup vs baseline: 2.0354x; 2.0354x over previous
//
#include <hip/hip_runtime.h>
#include <stdint.h>

#define B_   128
#define T_   64
#define V_   1024
#define TS_  64
#define H_   512
#define K_   (V_ + TS_)   // 1088

// ---------------------------------------------------------------------------
// Fused time-aware GRU scan, round 6.
//
// 64 WGs x 256 threads (4 waves). Global wave q = blk*4+w owns h[2q], h[2q+1];
// per-wave math identical to round 2 (register-resident W rows, butterfly).
//
// Protocol history:
//   r2 (11.2ms, PASS): 256 WGs all polling 512 tagged u64 words ->
//       256 same-line reqs/line/sweep -> ~1us/sweep, 2.8us/step. Contention.
//   r3 (18.3ms, PASS): buffer_inv per poll iter melted L1/L2. Never put
//       cache-maintenance in a spin loop.
//   r4/r5 (2x container death, zero signal): 32x512 leader+flags structure.
//       Can't find the bug on paper; abandoning that exact shape.
//   r6 (this): round-2 tagged-word protocol (proven twice), but only ONE
//       polling wave per WG (64 pollers -> 64 reqs/line/sweep ~ 200ns) with
//       LDS broadcast + one __syncthreads. Tags carry data+flag in one word:
//       observing the tag IS acquiring the data (no flag hop, no vmcnt).
//       BOUNDED SPIN: after 2^21 iters a leader goes dead and free-runs
//       (still publishing correctly-tagged data, so no one else blocks) ->
//       a protocol bug now ends in ~0.3s with absmax-fail, not a dead box.
//
// Overwrite safety (same induction as r2): tag==v from wave p implies p
// passed its step barrier, which implies p's WG leader finished reading
// slot (v+1)&1; all tags==v (all waves, all WGs) => every leader done with
// that slot => storing h(v+1) there is race-free. Leader's hs overwrite at
// step t+1 is gated on its own WG's tags==v+1 (waves read hs before storing).
//
// x row for step t+1 prefetched during step t (x-side is h-independent).
// Masked steps (t >= lens[b]) skipped; chain = sum(lens) ~ 4032 steps.
// Workspace: 8KB tagged h_buf. Poison tag 0xAAAAAAAA != any ver (<= ~8200).
// ---------------------------------------------------------------------------

__device__ __forceinline__ float sigmoidf_(float x) {
    return 1.0f / (1.0f + __expf(-x));
}
__device__ __forceinline__ float tanhf_(float x) {
    x = fminf(fmaxf(x, -15.0f), 15.0f);
    const float e = __expf(2.0f * x);
    return (e - 1.0f) / (e + 1.0f);
}

__global__ __launch_bounds__(256, 1) void gru_fused(
    const float* __restrict__ visit_emb, const float* __restrict__ intervals,
    const float* __restrict__ W_time, const float* __restrict__ b_time,
    const float* __restrict__ W_ih, const float* __restrict__ W_hh,
    const float* __restrict__ b_ih, const float* __restrict__ b_hh,
    const int* __restrict__ lens, uint64_t* h_buf /* [2][H_] tagged */,
    float* __restrict__ out)
{
    const int lane = threadIdx.x & 63;
    const int wave = threadIdx.x >> 6;        // 0..3
    const int q    = blockIdx.x * 4 + wave;   // 0..255 global wave id
    const int j0   = q * 2;
    const int j1   = j0 + 1;

    __shared__ float hs[H_];                  // per-WG broadcast of h

    // ---- register-resident W_hh rows (k = lane + 64u) -------------------
    float wr0[8], wr1[8], wz0[8], wz1[8], wn0[8], wn1[8];
    #pragma unroll
    for (int u = 0; u < 8; ++u) {
        const int k = lane + 64 * u;
        wr0[u] = W_hh[(size_t)j0 * H_ + k];
        wr1[u] = W_hh[(size_t)j1 * H_ + k];
        wz0[u] = W_hh[(size_t)(H_ + j0) * H_ + k];
        wz1[u] = W_hh[(size_t)(H_ + j1) * H_ + k];
        wn0[u] = W_hh[(size_t)(2 * H_ + j0) * H_ + k];
        wn1[u] = W_hh[(size_t)(2 * H_ + j1) * H_ + k];
    }
    // ---- W_ih rows: u<16 visit part, u==16 time part --------------------
    float ir0[17], ir1[17], iz0[17], iz1[17], in0[17], in1[17];
    #pragma unroll
    for (int u = 0; u < 16; ++u) {
        const int k = lane + 64 * u;
        ir0[u] = W_ih[(size_t)j0 * K_ + k];
        ir1[u] = W_ih[(size_t)j1 * K_ + k];
        iz0[u] = W_ih[(size_t)(H_ + j0) * K_ + k];
        iz1[u] = W_ih[(size_t)(H_ + j1) * K_ + k];
        in0[u] = W_ih[(size_t)(2 * H_ + j0) * K_ + k];
        in1[u] = W_ih[(size_t)(2 * H_ + j1) * K_ + k];
    }
    ir0[16] = W_ih[(size_t)j0 * K_ + V_ + lane];
    ir1[16] = W_ih[(size_t)j1 * K_ + V_ + lane];
    iz0[16] = W_ih[(size_t)(H_ + j0) * K_ + V_ + lane];
    iz1[16] = W_ih[(size_t)(H_ + j1) * K_ + V_ + lane];
    in0[16] = W_ih[(size_t)(2 * H_ + j0) * K_ + V_ + lane];
    in1[16] = W_ih[(size_t)(2 * H_ + j1) * K_ + V_ + lane];

    const float wt = W_time[lane];
    const float bt = b_time[lane];

    const float bir0 = b_ih[j0],          bir1 = b_ih[j1];
    const float biz0 = b_ih[H_ + j0],     biz1 = b_ih[H_ + j1];
    const float bin0 = b_ih[2 * H_ + j0], bin1 = b_ih[2 * H_ + j1];
    const float bhr0 = b_hh[j0],          bhr1 = b_hh[j1];
    const float bhz0 = b_hh[H_ + j0],     bhz1 = b_hh[H_ + j1];
    const float bhn0 = b_hh[2 * H_ + j0], bhn1 = b_hh[2 * H_ + j1];

    float hj0 = 0.0f, hj1 = 0.0f;
    uint32_t ver  = 1;    // ver 1 == initial zero state, lives in slot 1
    uint32_t dead = 0;    // leader watchdog state (wave-uniform)

    // publish initial tagged state (tag carries the flag; no waitcnt needed)
    if (lane < 2)
        __hip_atomic_store(&h_buf[(ver & 1) * H_ + j0 + lane],
                           (uint64_t)ver << 32,
                           __ATOMIC_RELAXED, __HIP_MEMORY_SCOPE_AGENT);

    float xv[16];     // current step's visit row (prefetched)
    float iv = 0.0f;  // current step's interval

    for (int b = 0; b < B_; ++b) {
        const int L = lens[b];
        if (L > 0) {
            iv = intervals[b * T_];
            const float* vrow = visit_emb + (size_t)(b * T_) * V_;
            #pragma unroll
            for (int u = 0; u < 16; ++u) xv[u] = vrow[lane + 64 * u];
        }
        for (int t = 0; t < L; ++t) {
            // ---- x-side dots from prefetched row (h-independent) --------
            const float xt = fmaf(iv, wt, bt);
            float ar0 = ir0[16] * xt, ar1 = ir1[16] * xt;
            float az0 = iz0[16] * xt, az1 = iz1[16] * xt;
            float xn0 = in0[16] * xt, xn1 = in1[16] * xt;
            #pragma unroll
            for (int u = 0; u < 16; ++u) {
                ar0 = fmaf(ir0[u], xv[u], ar0);
                ar1 = fmaf(ir1[u], xv[u], ar1);
                az0 = fmaf(iz0[u], xv[u], az0);
                az1 = fmaf(iz1[u], xv[u], az1);
                xn0 = fmaf(in0[u], xv[u], xn0);
                xn1 = fmaf(in1[u], xv[u], xn1);
            }
            // ---- prefetch next step's x row (hides under the poll) ------
            if (t + 1 < L) {
                iv = intervals[b * T_ + t + 1];
                const float* vrow = visit_emb + (size_t)(b * T_ + t + 1) * V_;
                #pragma unroll
                for (int u = 0; u < 16; ++u) xv[u] = vrow[lane + 64 * u];
            }

            // ---- leader wave: poll tagged words, broadcast via LDS ------
            if (wave == 0) {
                const uint64_t* src = h_buf + (ver & 1) * H_;
                uint64_t w[8];
                if (!dead) {
                    uint32_t tries = 0;
                    bool ok;
                    do {
                        ok = true;
                        #pragma unroll
                        for (int u = 0; u < 8; ++u) {
                            w[u] = __hip_atomic_load(&src[lane + 64 * u],
                                                     __ATOMIC_RELAXED,
                                                     __HIP_MEMORY_SCOPE_AGENT);
                            ok = ok && ((uint32_t)(w[u] >> 32) == ver);
                        }
                        if (++tries > (1u << 21)) { dead = 1; break; }
                    } while (!__all(ok));
                } else {
                    // watchdog tripped earlier: free-run with one sweep
                    #pragma unroll
                    for (int u = 0; u < 8; ++u)
                        w[u] = __hip_atomic_load(&src[lane + 64 * u],
                                                 __ATOMIC_RELAXED,
                                                 __HIP_MEMORY_SCOPE_AGENT);
                }
                #pragma unroll
                for (int u = 0; u < 8; ++u)
                    hs[lane + 64 * u] = __uint_as_float((uint32_t)w[u]);
            }
            __syncthreads();

            float h[8];
            #pragma unroll
            for (int u = 0; u < 8; ++u) h[u] = hs[lane + 64 * u];

            // ---- h-side dots; r/z merged with x-side, n kept split ------
            float hn0 = 0.0f, hn1 = 0.0f;
            #pragma unroll
            for (int u = 0; u < 8; ++u) {
                ar0 = fmaf(wr0[u], h[u], ar0);
                ar1 = fmaf(wr1[u], h[u], ar1);
                az0 = fmaf(wz0[u], h[u], az0);
                az1 = fmaf(wz1[u], h[u], az1);
                hn0 = fmaf(wn0[u], h[u], hn0);
                hn1 = fmaf(wn1[u], h[u], hn1);
            }
            #pragma unroll
            for (int m = 1; m < 64; m <<= 1) {
                ar0 += __shfl_xor(ar0, m, 64);
                ar1 += __shfl_xor(ar1, m, 64);
                az0 += __shfl_xor(az0, m, 64);
                az1 += __shfl_xor(az1, m, 64);
                xn0 += __shfl_xor(xn0, m, 64);
                xn1 += __shfl_xor(xn1, m, 64);
                hn0 += __shfl_xor(hn0, m, 64);
                hn1 += __shfl_xor(hn1, m, 64);
            }

            const float r0 = sigmoidf_(ar0 + bir0 + bhr0);
            const float r1 = sigmoidf_(ar1 + bir1 + bhr1);
            const float z0 = sigmoidf_(az0 + biz0 + bhz0);
            const float z1 = sigmoidf_(az1 + biz1 + bhz1);
            const float n0 = tanhf_(xn0 + bin0 + r0 * (hn0 + bhn0));
            const float n1 = tanhf_(xn1 + bin1 + r1 * (hn1 + bhn1));
            hj0 = (1.0f - z0) * n0 + z0 * hj0;
            hj1 = (1.0f - z1) * n1 + z1 * hj1;

            // ---- publish tagged h(ver+1) (data+flag in one word) --------
            ++ver;
            uint64_t* dst = h_buf + (ver & 1) * H_;
            const float hv = (lane == 0) ? hj0 : hj1;
            if (lane < 2)
                __hip_atomic_store(&dst[j0 + lane],
                    ((uint64_t)ver << 32) | (uint64_t)__float_as_uint(hv),
                    __ATOMIC_RELAXED, __HIP_MEMORY_SCOPE_AGENT);
        }
        // out[b] = h after sample b's (possibly empty) segment
        if (lane < 2) out[b * H_ + j0 + lane] = (lane == 0) ? hj0 : hj1;
    }
}

// ---------------------------------------------------------------------------
extern "C" void kernel_launch(void* const* d_in, const int* in_sizes, int n_in,
                              void* d_out, int out_size, void* d_ws, size_t ws_size,
                              hipStream_t stream)
{
    const float* visit_emb = (const float*)d_in[0];
    const float* intervals = (const float*)d_in[1];
    const float* W_time    = (const float*)d_in[2];
    const float* b_time    = (const float*)d_in[3];
    const float* W_ih      = (const float*)d_in[4];
    const float* W_hh      = (const float*)d_in[5];
    const float* b_ih      = (const float*)d_in[6];
    const float* b_hh      = (const float*)d_in[7];
    const int*   lens      = (const int*)d_in[8];
    float*       out       = (float*)d_out;

    // workspace: tagged h exchange buffer (2 x 512 x u64 = 8 KiB)
    uint64_t* h_buf = (uint64_t*)d_ws;

    gru_fused<<<64, 256, 0, stream>>>(visit_emb, intervals, W_time, b_time,
                                      W_ih, W_hh, b_ih, b_hh, lens, h_buf, out);
}